// Round 5
// baseline (402.030 us; speedup 1.0000x reference)
//
#include <hip/hip_runtime.h>

#define GN_EPS 1e-5f

typedef float f32x4 __attribute__((ext_vector_type(4)));

// Problem constants (fixed by setup_inputs): N=131072, U=256, B=64
constexpr int U       = 256;                 // units (row length, 1 KB = 64 lanes x 16 B)
constexpr int NPG     = 2048;                // nodes (rows) per graph
constexpr int NGRAPH  = 64;
constexpr int UF4     = U / 4;               // 64 float4 per row

// Kernel 1: partial stats.  CH=32 -> 2048 blocks (8/CU, 32 waves/CU max occupancy)
constexpr int CH      = 32;                  // row-chunks per graph
constexpr int RPC     = NPG / CH;            // 64 rows per chunk
constexpr int K1_BLK  = 256;                 // 4 waves
constexpr int K1_WAVES = K1_BLK / 64;
constexpr int K1_ITERS = RPC / K1_WAVES;     // 16 rows per wave

// Kernel 3: normalize (at roofline as of round 4 — do not touch)
constexpr int CH3     = 64;                  // 4096 blocks
constexpr int RPC3    = NPG / CH3;           // 32 rows per chunk
constexpr int K3_BLK  = 256;
constexpr int K3_ITERS = (RPC3 * UF4) / K3_BLK; // 8 float4 per thread

// Workspace layout (floats), total ~4.2 MB:
constexpr size_t WS_SUM_OFF  = 0;
constexpr size_t WS_SQ_OFF   = (size_t)NGRAPH * CH * U;
constexpr size_t WS_MEAN_OFF = WS_SQ_OFF + (size_t)NGRAPH * CH * U;
constexpr size_t WS_INV_OFF  = WS_MEAN_OFF + (size_t)NGRAPH * U;

// ---------- K1: per-(graph, chunk) partial column sums over 64 full rows ----------
__global__ __launch_bounds__(K1_BLK) void gn_partial(
    const float* __restrict__ x, float* __restrict__ ws)
{
    const int chunk = blockIdx.x & (CH - 1);
    const int graph = blockIdx.x / CH;
    const int t     = threadIdx.x;
    const int wave  = t >> 6;
    const int lane  = t & 63;                // lane <-> float4 column group

    // wave w reads rows w, w+4, w+8, ... each as one contiguous 1 KB wave-load
    const size_t row0 = (size_t)graph * NPG + (size_t)chunk * RPC + wave;
    const f32x4* xr = reinterpret_cast<const f32x4*>(x) + row0 * UF4 + lane;

    f32x4 s = (f32x4)0.f;
    f32x4 q = (f32x4)0.f;
#pragma unroll 8
    for (int i = 0; i < K1_ITERS; ++i) {
        const f32x4 v = xr[(size_t)i * K1_WAVES * UF4];
        s += v;
        q += v * v;
    }

    __shared__ f32x4 ssum[K1_WAVES][64];
    __shared__ f32x4 ssq [K1_WAVES][64];
    ssum[wave][lane] = s;
    ssq [wave][lane] = q;
    __syncthreads();

    if (t < 64) {
        f32x4 s2 = ssum[0][t];
        f32x4 q2 = ssq [0][t];
#pragma unroll
        for (int w = 1; w < K1_WAVES; ++w) {
            s2 += ssum[w][t];
            q2 += ssq [w][t];
        }
        const size_t o = ((size_t)graph * CH + chunk) * UF4 + t;
        reinterpret_cast<f32x4*>(ws + WS_SUM_OFF)[o] = s2;
        reinterpret_cast<f32x4*>(ws + WS_SQ_OFF )[o] = q2;
    }
}

// ---------- K2: reduce CH partials -> mean, 1/(std+eps) per (graph, unit) ----------
__global__ __launch_bounds__(U) void gn_finalize(float* __restrict__ ws)
{
    const int graph = blockIdx.x;
    const int t     = threadIdx.x;           // unit index

    const float* psum = ws + WS_SUM_OFF + (size_t)graph * CH * U + t;
    const float* psq  = ws + WS_SQ_OFF  + (size_t)graph * CH * U + t;
    float s = 0.f, q = 0.f;
#pragma unroll
    for (int c = 0; c < CH; ++c) {
        s += psum[(size_t)c * U];
        q += psq [(size_t)c * U];
    }
    const float invn = 1.0f / (float)NPG;
    const float mean = s * invn;
    const float var  = fmaxf(q * invn - mean * mean, 0.f);
    ws[WS_MEAN_OFF + (size_t)graph * U + t] = mean;
    ws[WS_INV_OFF  + (size_t)graph * U + t] = 1.0f / (sqrtf(var) + GN_EPS);
}

// ---------- K3: normalize + affine, pure streaming, reg-resident stats ----------
__global__ __launch_bounds__(K3_BLK) void gn_normalize(
    const float* __restrict__ x,
    const float* __restrict__ gamma,
    const float* __restrict__ beta,
    const float* __restrict__ ws,
    float* __restrict__ out)
{
    const int chunk = blockIdx.x & (CH3 - 1);
    const int graph = blockIdx.x / CH3;
    const int t     = threadIdx.x;

    // K3_BLK % 64 == 0 => thread t always touches float4-column (t & 63):
    // stats are loop-invariant registers, no LDS, no barrier.
    const int f4 = t & (UF4 - 1);
    const f32x4 m  = reinterpret_cast<const f32x4*>(ws + WS_MEAN_OFF + (size_t)graph * U)[f4];
    const f32x4 iv = reinterpret_cast<const f32x4*>(ws + WS_INV_OFF  + (size_t)graph * U)[f4];

    const size_t f4base = ((size_t)graph * NPG + (size_t)chunk * RPC3) * UF4;
    const f32x4* xv = reinterpret_cast<const f32x4*>(x)     + f4base;
    const f32x4* gv = reinterpret_cast<const f32x4*>(gamma) + f4base;
    const f32x4* bv = reinterpret_cast<const f32x4*>(beta)  + f4base;
    f32x4*       ov = reinterpret_cast<f32x4*>(out)         + f4base;

#pragma unroll 4
    for (int i = 0; i < K3_ITERS; ++i) {
        const int idx = i * K3_BLK + t;
        const f32x4 v  = xv[idx];                               // normal: L3-hot from K1
        const f32x4 g4 = __builtin_nontemporal_load(gv + idx);  // single-use streams
        const f32x4 b4 = __builtin_nontemporal_load(bv + idx);
        const f32x4 o  = g4 * ((v - m) * iv) + b4;
        __builtin_nontemporal_store(o, ov + idx);               // don't evict reads
    }
}

extern "C" void kernel_launch(void* const* d_in, const int* in_sizes, int n_in,
                              void* d_out, int out_size, void* d_ws, size_t ws_size,
                              hipStream_t stream) {
    const float* x     = (const float*)d_in[0];
    const float* gamma = (const float*)d_in[1];
    const float* beta  = (const float*)d_in[2];
    float* out = (float*)d_out;
    float* ws  = (float*)d_ws;
    (void)in_sizes; (void)n_in; (void)out_size; (void)ws_size;

    gn_partial  <<<NGRAPH * CH,  K1_BLK, 0, stream>>>(x, ws);
    gn_finalize <<<NGRAPH,       U,      0, stream>>>(ws);
    gn_normalize<<<NGRAPH * CH3, K3_BLK, 0, stream>>>(x, gamma, beta, ws, out);
}